// Round 6
// baseline (627.337 us; speedup 1.0000x reference)
//
#include <hip/hip_runtime.h>

#define B_ 16
#define L_ 2048
#define D_ 128
#define TQ 64
#define TK 32
#define NW 4

typedef __attribute__((ext_vector_type(8))) short bf16x8;
typedef __attribute__((ext_vector_type(4))) float f32x4;
typedef __attribute__((ext_vector_type(4))) unsigned short us4;
typedef __attribute__((ext_vector_type(4))) unsigned int u32x4;

static __device__ __forceinline__ unsigned short f2bf(float x) {
  unsigned int u = __float_as_uint(x);
  u += 0x7fff + ((u >> 16) & 1);   // round-to-nearest-even
  return (unsigned short)(u >> 16);
}

// ws layout (bf16 elements): qs [B,L,D] @ 0 ; ks [B,L,D] @ 4.19M ; vt [B,D,L] @ 8.39M
#define QS_OFF 0
#define KS_OFF (B_ * L_ * D_)
#define VT_OFF (2 * B_ * L_ * D_)

// ---- prepass 1: Q (pre-scaled) and K -> bf16 ----
__global__ __launch_bounds__(256) void conv_qk(const float* __restrict__ Q,
                                               const float* __restrict__ K,
                                               unsigned short* __restrict__ ws) {
  const int half = 4096;
  const bool isQ = (int)blockIdx.x < half;
  const float* src = isQ ? Q : K;
  unsigned short* dst = ws + (isQ ? QS_OFF : KS_OFF);
  const float s = isQ ? 0.08838834764831845f : 1.0f;  // 1/sqrt(128)
  size_t idx = ((size_t)(blockIdx.x & (half - 1)) * 256 + threadIdx.x) * 4;
  float4 v = *(const float4*)(src + idx);
  us4 u = { f2bf(v.x * s), f2bf(v.y * s), f2bf(v.z * s), f2bf(v.w * s) };
  *(us4*)(dst + idx) = u;
}

// ---- prepass 2: V -> V^T bf16 ([B,D,L]), 64x64 LDS-tiled transpose ----
__global__ __launch_bounds__(256) void conv_vt(const float* __restrict__ V,
                                               unsigned short* __restrict__ ws) {
  __shared__ unsigned short st[64 * 72];
  unsigned short* vt = ws + VT_OFF;
  const int b = blockIdx.x >> 6;
  const int t = blockIdx.x & 63;
  const int l0 = (t >> 1) * 64, d0 = (t & 1) * 64;
  const int tid = threadIdx.x;
  #pragma unroll
  for (int i = 0; i < 4; ++i) {
    int s = i * 256 + tid;
    int r = s >> 4, c = (s & 15) * 4;
    float4 v = *(const float4*)(V + ((size_t)b * L_ + l0 + r) * D_ + d0 + c);
    st[(c + 0) * 72 + r] = f2bf(v.x);
    st[(c + 1) * 72 + r] = f2bf(v.y);
    st[(c + 2) * 72 + r] = f2bf(v.z);
    st[(c + 3) * 72 + r] = f2bf(v.w);
  }
  __syncthreads();
  #pragma unroll
  for (int i = 0; i < 4; ++i) {
    int s = i * 256 + tid;
    int dr = s >> 4, lc = (s & 15) * 4;
    us4 u = *(const us4*)&st[dr * 72 + lc];
    *(us4*)(vt + ((size_t)b * D_ + d0 + dr) * L_ + l0 + lc) = u;
  }
}

// ---- main: 2-pass flash attention, S^T layout (mfma(K,Q)); TK=32 tiles.
// ZERO LDS, ZERO barriers: K/V fragments direct from global (L2/L3-resident,
// FETCH_SIZE=17MB proved it), 2-tile register double-buffer for K, and the
// P->A-frag transform done by an in-register shuffle butterfly (xor32, xor16).
// Grid caps occupancy at 2 blocks/CU (8 waves), so VGPRs are free up to 256.
__global__ __launch_bounds__(256, 2) void attn_main(const unsigned short* __restrict__ ws,
                                                    float* __restrict__ Out) {
  const int tid  = threadIdx.x;
  const int w    = tid >> 6;
  const int lane = tid & 63;
  const int quad = lane >> 4;
  const int l16  = lane & 15;
  const int bq   = quad >> 1;   // quad bit1
  const int cq   = quad & 1;    // quad bit0

  // bijective XCD swizzle: 512 blocks = 8 XCDs x 64; XCD i gets batches 2i, 2i+1
  const int bid    = (int)blockIdx.x;
  const int newbid = (bid & 7) * 64 + (bid >> 3);
  const int b  = newbid >> 5;
  const int q0 = (newbid & 31) * TQ;
  const int gq = q0 + w * 16;

  const unsigned short* qs = ws + QS_OFF;
  const unsigned short* ks = ws + KS_OFF + (size_t)b * L_ * D_;
  const unsigned short* vt = ws + VT_OFF + (size_t)b * D_ * L_;
  float* ctx   = Out;
  float* probs = Out + (size_t)B_ * L_ * D_;

  // K A-frags for one 32x128 tile: A[m = nb*16+l16][k = kb*32 + quad*8 + j]
  auto loadK = [&](bf16x8 (&bk)[8], int kt) {
    #pragma unroll
    for (int nb = 0; nb < 2; ++nb)
      #pragma unroll
      for (int kb = 0; kb < 4; ++kb)
        bk[nb * 4 + kb] = *(const bf16x8*)(ks + (size_t)(kt * TK + nb * 16 + l16) * D_ + kb * 32 + quad * 8);
  };
  // V B-frags: B[k = quad*8 + j][d = nb*16 + l16] from vt[d][kt*32 + quad*8 + j]
  auto loadV = [&](bf16x8 (&bv)[8], int kt) {
    #pragma unroll
    for (int nb = 0; nb < 8; ++nb)
      bv[nb] = *(const bf16x8*)(vt + (size_t)(nb * 16 + l16) * L_ + kt * TK + quad * 8);
  };

  // Q fragments (one-time, 16B/lane), B-operand of swapped MFMA.
  bf16x8 aq[4];
  #pragma unroll
  for (int kb = 0; kb < 4; ++kb)
    aq[kb] = *(const bf16x8*)(qs + ((size_t)(b * L_ + gq + l16)) * D_ + kb * 32 + quad * 8);
  // Retire aq loads and detach from defs: no vmcnt ever re-inserted for them.
  asm volatile("s_waitcnt vmcnt(0)" ::: "memory");
  #pragma unroll
  for (int kb = 0; kb < 4; ++kb) asm volatile("" : "+v"(aq[kb]));

  // ============ pass 1: row sums of exp(S). Register-double-buffered K. ============
  float lsum = 0.f;  // partial over k with (k>>2)&3 == quad, for q = gq + l16
  {
    bf16x8 bk0[8], bk1[8];
    auto qkSum = [&](bf16x8 (&bk)[8]) {
      #pragma unroll
      for (int nb = 0; nb < 2; ++nb) {
        f32x4 c = {0.f, 0.f, 0.f, 0.f};
        #pragma unroll
        for (int kb = 0; kb < 4; ++kb)
          c = __builtin_amdgcn_mfma_f32_16x16x32_bf16(bk[nb * 4 + kb], aq[kb], c, 0, 0, 0);
        #pragma unroll
        for (int r = 0; r < 4; ++r) lsum += __expf(c[r]);
      }
    };
    loadK(bk0, 0);
    for (int kt = 0; kt < L_ / TK; kt += 2) {
      loadK(bk1, kt + 1);
      qkSum(bk0);
      if (kt + 2 < L_ / TK) loadK(bk0, kt + 2);
      qkSum(bk1);
    }
  }

  // quads partition k-space: combine 4 partials (lanes l16, +16, +32, +48)
  float s_ = lsum;
  s_ += __shfl_xor(s_, 16);
  s_ += __shfl_xor(s_, 32);
  const float rl = 1.0f / s_;  // 1/rowsum for q = gq + l16

  // ============ pass 2: recompute S^T, write probs (dwordx4), ctx = P @ V ============
  f32x4 acc[8];
  #pragma unroll
  for (int nb = 0; nb < 8; ++nb) { f32x4 z = {0.f, 0.f, 0.f, 0.f}; acc[nb] = z; }

  bf16x8 bkA[8], bkB[8];
  loadK(bkA, 0);

  auto tile = [&](bf16x8 (&bkCur)[8], bf16x8 (&bkNxt)[8], int kt) {
    // V first (older in vmem queue), then next-K prefetch (newest, stays in flight)
    bf16x8 bv[8];
    loadV(bv, kt);
    if (kt + 1 < L_ / TK) loadK(bkNxt, kt + 1);

    // ---- S^T: lane holds P[q=l16][k = kt*32 + nb*16 + quad*4 + r] ----
    float p[2][4];
    __builtin_amdgcn_s_setprio(1);
    #pragma unroll
    for (int nb = 0; nb < 2; ++nb) {
      f32x4 c = {0.f, 0.f, 0.f, 0.f};
      #pragma unroll
      for (int kb = 0; kb < 4; ++kb)
        c = __builtin_amdgcn_mfma_f32_16x16x32_bf16(bkCur[nb * 4 + kb], aq[kb], c, 0, 0, 0);
      #pragma unroll
      for (int r = 0; r < 4; ++r) p[nb][r] = __expf(c[r]) * rl;
    }
    __builtin_amdgcn_s_setprio(0);

    // probs: 16B vector stores
    #pragma unroll
    for (int nb = 0; nb < 2; ++nb) {
      f32x4 pv = {p[nb][0], p[nb][1], p[nb][2], p[nb][3]};
      *(f32x4*)&probs[(size_t)(b * L_ + gq + l16) * L_ + kt * TK + nb * 16 + quad * 4] = pv;
    }

    // ---- in-register butterfly: S^T frags -> PV A-frag (replaces sP LDS trip) ----
    // word(nb,h) = bf16x2(p[nb][2h], p[nb][2h+1]), k-base = 16nb + 4quad + 2h.
    // Dest: quad_t = 2nb + (quad_s>>1), slot j = 2(quad_s&1) + h.
    unsigned q0w = (unsigned)f2bf(p[0][0]) | ((unsigned)f2bf(p[0][1]) << 16);
    unsigned q1w = (unsigned)f2bf(p[0][2]) | ((unsigned)f2bf(p[0][3]) << 16);
    unsigned q2w = (unsigned)f2bf(p[1][0]) | ((unsigned)f2bf(p[1][1]) << 16);
    unsigned q3w = (unsigned)f2bf(p[1][2]) | ((unsigned)f2bf(p[1][3]) << 16);
    // stage A (xor32, swap quad bit1): keep nb == bq, send nb == 1-bq
    unsigned keep0 = bq ? q2w : q0w;
    unsigned keep1 = bq ? q3w : q1w;
    unsigned send0 = bq ? q0w : q2w;
    unsigned send1 = bq ? q1w : q3w;
    unsigned r0 = __shfl_xor(send0, 32);
    unsigned r1 = __shfl_xor(send1, 32);
    // stage B (xor16, swap quad bit0): local pair stays iff bq==cq
    const bool keepLocal = (bq == cq);
    unsigned sB0 = keepLocal ? r0 : keep0;
    unsigned sB1 = keepLocal ? r1 : keep1;
    unsigned kB0 = keepLocal ? keep0 : r0;
    unsigned kB1 = keepLocal ? keep1 : r1;
    unsigned t0 = __shfl_xor(sB0, 16);
    unsigned t1 = __shfl_xor(sB1, 16);
    // slots: kB pair has src qs&1 == cq -> j = 2cq+h ; t pair -> j = 2(1-cq)+h
    unsigned w0 = cq ? t0 : kB0;
    unsigned w1 = cq ? t1 : kB1;
    unsigned w2 = cq ? kB0 : t0;
    unsigned w3 = cq ? kB1 : t1;
    u32x4 awv = {w0, w1, w2, w3};
    bf16x8 ap = __builtin_bit_cast(bf16x8, awv);

    // ---- PV ----
    __builtin_amdgcn_s_setprio(1);
    #pragma unroll
    for (int nb = 0; nb < 8; ++nb)
      acc[nb] = __builtin_amdgcn_mfma_f32_16x16x32_bf16(ap, bv[nb], acc[nb], 0, 0, 0);
    __builtin_amdgcn_s_setprio(0);
  };

  for (int kt = 0; kt < L_ / TK; kt += 2) {
    tile(bkA, bkB, kt);
    tile(bkB, bkA, kt + 1);
  }

  // ---- epilogue: ctx (row q = quad*4+r, col d = nb*16+l16) ----
  #pragma unroll
  for (int nb = 0; nb < 8; ++nb) {
    #pragma unroll
    for (int r = 0; r < 4; ++r)
      ctx[(size_t)(b * L_ + gq + quad * 4 + r) * D_ + nb * 16 + l16] = acc[nb][r];
  }
}

extern "C" void kernel_launch(void* const* d_in, const int* in_sizes, int n_in,
                              void* d_out, int out_size, void* d_ws, size_t ws_size,
                              hipStream_t stream) {
  const float* q = (const float*)d_in[0];
  const float* k = (const float*)d_in[1];
  const float* v = (const float*)d_in[2];
  unsigned short* ws = (unsigned short*)d_ws;
  float* out = (float*)d_out;
  conv_qk<<<dim3(8192), dim3(256), 0, stream>>>(q, k, ws);
  conv_vt<<<dim3(1024), dim3(256), 0, stream>>>(v, ws);
  attn_main<<<dim3(B_ * (L_ / TQ)), dim3(256), 0, stream>>>(ws, out);
}